// Round 1
// baseline (179.624 us; speedup 1.0000x reference)
//
#include <hip/hip_runtime.h>
#include <math.h>

#define D 256            // feature dim (D_IN == D_OUT == 256)
#define MAXNORM (1.0f - 4e-3f)   // (1 - BALL_EPS)/sqrt(c), c = 1
#define MIN_NORM 1e-15f

__device__ __forceinline__ float wave_reduce_sum(float v) {
    #pragma unroll
    for (int m = 32; m >= 1; m >>= 1) v += __shfl_xor(v, m, 64);
    return v;
}

__device__ __forceinline__ float dot4(const float4& a, const float4& b) {
    return a.x * b.x + a.y * b.y + a.z * b.z + a.w * b.w;
}

__device__ __forceinline__ float artanh_clip(float x) {
    x = fminf(fmaxf(x, -1.0f + 1e-7f), 1.0f - 1e-7f);
    return 0.5f * (log1pf(x) - log1pf(-x));
}

// ---------------------------------------------------------------------------
// Kernel 1: hyp_bias = proj(expmap0(bias, c=1), c=1); also store ||hyp_bias||^2
// One wave (64 threads), lane l owns bias[4l..4l+3].
// ---------------------------------------------------------------------------
__global__ void bias_kernel(const float* __restrict__ bias, float* __restrict__ hb) {
    int l = threadIdx.x;  // 0..63
    float4 v = *(const float4*)(bias + 4 * l);
    float bn = fmaxf(sqrtf(wave_reduce_sum(dot4(v, v))), MIN_NORM);
    float f = tanhf(bn) / bn;       // sqrt(c) = 1
    float4 h = make_float4(v.x * f, v.y * f, v.z * f, v.w * f);
    // proj
    float hn = fmaxf(sqrtf(wave_reduce_sum(dot4(h, h))), MIN_NORM);
    float s = (hn > MAXNORM) ? (MAXNORM / hn) : 1.0f;
    h.x *= s; h.y *= s; h.z *= s; h.w *= s;
    *(float4*)(hb + 4 * l) = h;
    float y2 = wave_reduce_sum(dot4(h, h));
    if (l == 0) hb[D] = y2;
}

// ---------------------------------------------------------------------------
// Kernel 2: mx = x @ W^T   (fp32, LDS-tiled 64x64, 4x4 micro-tiles)
// W is [256 cols][256 k] row-major; mx[n][col] = sum_k x[n][k]*W[col][k]
// ---------------------------------------------------------------------------
#define TN 64
#define TM 64
#define TK 16

__global__ __launch_bounds__(256) void gemm_kernel(
    const float* __restrict__ X, const float* __restrict__ W,
    float* __restrict__ MX, int N)
{
    __shared__ float As[TK][TN + 4];  // +4 keeps 16B row alignment, breaks conflicts
    __shared__ float Bs[TK][TM + 4];
    const int tid = threadIdx.x;
    const int tx = tid & 15, ty = tid >> 4;
    const int r0 = blockIdx.x * TN;
    const int c0 = blockIdx.y * TM;
    const int lr = tid >> 2;           // 0..63 (row within tile for loads)
    const int lk = (tid & 3) * 4;      // 0,4,8,12 (k offset within tile)

    float acc[4][4] = {};

    for (int k0 = 0; k0 < D; k0 += TK) {
        int grow = r0 + lr;
        float4 av = make_float4(0.f, 0.f, 0.f, 0.f);
        if (grow < N) av = *(const float4*)(X + (size_t)grow * D + k0 + lk);
        As[lk + 0][lr] = av.x; As[lk + 1][lr] = av.y;
        As[lk + 2][lr] = av.z; As[lk + 3][lr] = av.w;
        float4 bv = *(const float4*)(W + (size_t)(c0 + lr) * D + k0 + lk);
        Bs[lk + 0][lr] = bv.x; Bs[lk + 1][lr] = bv.y;
        Bs[lk + 2][lr] = bv.z; Bs[lk + 3][lr] = bv.w;
        __syncthreads();

        #pragma unroll
        for (int kk = 0; kk < TK; ++kk) {
            float4 a = *(const float4*)&As[kk][ty * 4];
            float4 b = *(const float4*)&Bs[kk][tx * 4];
            float avr[4] = {a.x, a.y, a.z, a.w};
            float bvr[4] = {b.x, b.y, b.z, b.w};
            #pragma unroll
            for (int i = 0; i < 4; ++i)
                #pragma unroll
                for (int j = 0; j < 4; ++j)
                    acc[i][j] = fmaf(avr[i], bvr[j], acc[i][j]);
        }
        __syncthreads();
    }

    #pragma unroll
    for (int i = 0; i < 4; ++i) {
        int row = r0 + ty * 4 + i;
        if (row < N) {
            float4 o = make_float4(acc[i][0], acc[i][1], acc[i][2], acc[i][3]);
            *(float4*)(MX + (size_t)row * D + c0 + tx * 4) = o;
        }
    }
}

// ---------------------------------------------------------------------------
// Kernel 3: per-row hyperbolic ops  (one wave per row)
// h = proj(mobius_matvec tail); h = proj(mobius_add(h, hyp_bias)); xt = logmap0(h)
// ---------------------------------------------------------------------------
__global__ __launch_bounds__(256) void rowops_kernel(
    const float* __restrict__ X, const float* __restrict__ MX,
    const float* __restrict__ HB, float* __restrict__ XT, int N)
{
    int wave = (int)((blockIdx.x * (size_t)blockDim.x + threadIdx.x) >> 6);
    int l = threadIdx.x & 63;
    if (wave >= N) return;

    const float4 xv  = *(const float4*)(X  + (size_t)wave * D + 4 * l);
    const float4 mxv = *(const float4*)(MX + (size_t)wave * D + 4 * l);

    float xn  = fmaxf(sqrtf(wave_reduce_sum(dot4(xv,  xv))),  MIN_NORM);
    float mxn = fmaxf(sqrtf(wave_reduce_sum(dot4(mxv, mxv))), MIN_NORM);

    // mobius_matvec (sc = 1): res = tanh(mxn/xn * artanh(xn)) * mx / mxn
    float r = (mxn / xn) * artanh_clip(xn);
    float f = tanhf(r) / mxn;
    float4 h = make_float4(mxv.x * f, mxv.y * f, mxv.z * f, mxv.w * f);

    // proj
    float hss = wave_reduce_sum(dot4(h, h));
    float hn = fmaxf(sqrtf(hss), MIN_NORM);
    float s = (hn > MAXNORM) ? (MAXNORM / hn) : 1.0f;
    h.x *= s; h.y *= s; h.z *= s; h.w *= s;
    float x2 = hss * s * s;   // ||h||^2 after proj

    // mobius_add(h, hb), c = 1
    const float4 y = *(const float4*)(HB + 4 * l);
    float y2 = HB[D];
    float xy = wave_reduce_sum(dot4(h, y));
    float ch = 1.0f + 2.0f * xy + y2;   // coefficient on h
    float cy = 1.0f - x2;               // coefficient on y
    float den = fmaxf(1.0f + 2.0f * xy + x2 * y2, MIN_NORM);
    float inv = 1.0f / den;
    float4 g = make_float4((ch * h.x + cy * y.x) * inv,
                           (ch * h.y + cy * y.y) * inv,
                           (ch * h.z + cy * y.z) * inv,
                           (ch * h.w + cy * y.w) * inv);

    // proj
    float gss = wave_reduce_sum(dot4(g, g));
    float gn = fmaxf(sqrtf(gss), MIN_NORM);
    float s2 = (gn > MAXNORM) ? (MAXNORM / gn) : 1.0f;
    g.x *= s2; g.y *= s2; g.z *= s2; g.w *= s2;

    // logmap0: xt = artanh(pn)/pn * g
    float pn = fmaxf(gn * s2, MIN_NORM);
    float lf = artanh_clip(pn) / pn;
    float4 xt = make_float4(g.x * lf, g.y * lf, g.z * lf, g.w * lf);
    *(float4*)(XT + (size_t)wave * D + 4 * l) = xt;
}

// ---------------------------------------------------------------------------
// Kernel 4: sparse aggregation + HypAct   (one wave per node)
// support = sum_e val[e]*xt[col[e]];  h = proj(expmap0(support));
// out = proj(expmap0(relu(logmap0(h))))
// ---------------------------------------------------------------------------
__global__ __launch_bounds__(256) void agg_kernel(
    const int* __restrict__ rows, const int* __restrict__ cols,
    const float* __restrict__ vals, const float* __restrict__ XT,
    float* __restrict__ OUT, int N, int E)
{
    int node = (int)((blockIdx.x * (size_t)blockDim.x + threadIdx.x) >> 6);
    int l = threadIdx.x & 63;
    if (node >= N) return;

    // CSR range of this node via binary search on sorted rows
    int lo = 0, hi = E;
    while (lo < hi) { int mid = (lo + hi) >> 1; if (rows[mid] < node) lo = mid + 1; else hi = mid; }
    int start = lo;
    hi = E;
    while (lo < hi) { int mid = (lo + hi) >> 1; if (rows[mid] <= node) lo = mid + 1; else hi = mid; }
    int end = lo;

    const float4* xt4 = (const float4*)XT;
    float4 acc = make_float4(0.f, 0.f, 0.f, 0.f);
    for (int e = start; e < end; ++e) {
        float v = vals[e];
        int c = cols[e];
        float4 m = xt4[(size_t)c * 64 + l];
        acc.x = fmaf(v, m.x, acc.x);
        acc.y = fmaf(v, m.y, acc.y);
        acc.z = fmaf(v, m.z, acc.z);
        acc.w = fmaf(v, m.w, acc.w);
    }

    // expmap0
    float un = fmaxf(sqrtf(wave_reduce_sum(dot4(acc, acc))), MIN_NORM);
    float f = tanhf(un) / un;
    float4 h = make_float4(acc.x * f, acc.y * f, acc.z * f, acc.w * f);
    // proj
    float hn = fmaxf(sqrtf(wave_reduce_sum(dot4(h, h))), MIN_NORM);
    float s = (hn > MAXNORM) ? (MAXNORM / hn) : 1.0f;
    h.x *= s; h.y *= s; h.z *= s; h.w *= s;
    // logmap0 + relu
    float pn = fmaxf(hn * s, MIN_NORM);
    float lf = artanh_clip(pn) / pn;
    float4 t = make_float4(fmaxf(h.x * lf, 0.f), fmaxf(h.y * lf, 0.f),
                           fmaxf(h.z * lf, 0.f), fmaxf(h.w * lf, 0.f));
    // expmap0 (c_out = 1)
    float un2 = fmaxf(sqrtf(wave_reduce_sum(dot4(t, t))), MIN_NORM);
    float f2 = tanhf(un2) / un2;
    float4 o = make_float4(t.x * f2, t.y * f2, t.z * f2, t.w * f2);
    // proj
    float on = fmaxf(sqrtf(wave_reduce_sum(dot4(o, o))), MIN_NORM);
    float s2 = (on > MAXNORM) ? (MAXNORM / on) : 1.0f;
    o.x *= s2; o.y *= s2; o.z *= s2; o.w *= s2;

    *(float4*)(OUT + (size_t)node * D + 4 * l) = o;
}

// ---------------------------------------------------------------------------
extern "C" void kernel_launch(void* const* d_in, const int* in_sizes, int n_in,
                              void* d_out, int out_size, void* d_ws, size_t ws_size,
                              hipStream_t stream) {
    const float* X    = (const float*)d_in[0];
    const float* W    = (const float*)d_in[1];
    const float* bias = (const float*)d_in[2];
    const float* vals = (const float*)d_in[3];
    const int*   rows = (const int*)d_in[4];
    const int*   cols = (const int*)d_in[5];
    float* OUT = (float*)d_out;

    const int N = in_sizes[0] / D;   // 10000
    const int E = in_sizes[3];       // 320000

    float* ws = (float*)d_ws;
    float* HB = ws;                  // 256 + 1 floats (pad to 512)
    float* XT = ws + 512;            // N*256 floats
    float* MX = OUT;                 // use d_out as GEMM scratch; overwritten by agg

    bias_kernel<<<1, 64, 0, stream>>>(bias, HB);
    dim3 ggrid((N + TN - 1) / TN, D / TM);
    gemm_kernel<<<ggrid, 256, 0, stream>>>(X, W, MX, N);
    int wave_blocks = (N + 3) / 4;   // 4 waves (rows) per 256-thread block
    rowops_kernel<<<wave_blocks, 256, 0, stream>>>(X, MX, HB, XT, N);
    agg_kernel<<<wave_blocks, 256, 0, stream>>>(rows, cols, vals, XT, OUT, N, E);
}

// Round 2
// 147.266 us; speedup vs baseline: 1.2197x; 1.2197x over previous
//
#include <hip/hip_runtime.h>
#include <math.h>

#define D 256            // feature dim (D_IN == D_OUT == 256)
#define MAXNORM (1.0f - 4e-3f)   // (1 - BALL_EPS)/sqrt(c), c = 1
#define MIN_NORM 1e-15f

__device__ __forceinline__ float wave_reduce_sum(float v) {
    #pragma unroll
    for (int m = 32; m >= 1; m >>= 1) v += __shfl_xor(v, m, 64);
    return v;
}

__device__ __forceinline__ float dot4(const float4& a, const float4& b) {
    return a.x * b.x + a.y * b.y + a.z * b.z + a.w * b.w;
}

__device__ __forceinline__ float artanh_clip(float x) {
    x = fminf(fmaxf(x, -1.0f + 1e-7f), 1.0f - 1e-7f);
    return 0.5f * (log1pf(x) - log1pf(-x));
}

// ---------------------------------------------------------------------------
// Kernel 1: hyp_bias = proj(expmap0(bias, c=1), c=1); also store ||hyp_bias||^2
// ---------------------------------------------------------------------------
__global__ void bias_kernel(const float* __restrict__ bias, float* __restrict__ hb) {
    int l = threadIdx.x;  // 0..63
    float4 v = *(const float4*)(bias + 4 * l);
    float bn = fmaxf(sqrtf(wave_reduce_sum(dot4(v, v))), MIN_NORM);
    float f = tanhf(bn) / bn;       // sqrt(c) = 1
    float4 h = make_float4(v.x * f, v.y * f, v.z * f, v.w * f);
    float hn = fmaxf(sqrtf(wave_reduce_sum(dot4(h, h))), MIN_NORM);
    float s = (hn > MAXNORM) ? (MAXNORM / hn) : 1.0f;
    h.x *= s; h.y *= s; h.z *= s; h.w *= s;
    *(float4*)(hb + 4 * l) = h;
    float y2 = wave_reduce_sum(dot4(h, h));
    if (l == 0) hb[D] = y2;
}

// ---------------------------------------------------------------------------
// Kernel 1b: row_ptr from sorted adj_row. rowptr[r] = first e with rows[e] >= r.
// Edge-parallel run-boundary fill; covers all r in [0, N].
// ---------------------------------------------------------------------------
__global__ __launch_bounds__(256) void rowptr_kernel(
    const int* __restrict__ rows, int* __restrict__ rowptr, int N, int E)
{
    int e = blockIdx.x * blockDim.x + threadIdx.x;
    if (e >= E) return;
    int r1 = rows[e];
    if (e == 0) {
        for (int r = 0; r <= r1; ++r) rowptr[r] = 0;
    } else {
        int r0 = rows[e - 1];
        for (int r = r0 + 1; r <= r1; ++r) rowptr[r] = e;
    }
    if (e == E - 1) {
        for (int r = r1 + 1; r <= N; ++r) rowptr[r] = E;
    }
}

// ---------------------------------------------------------------------------
// Kernel 2: mx = x @ W^T   (fp32, LDS-tiled 64x64, 4x4 micro-tiles)
// ---------------------------------------------------------------------------
#define TN 64
#define TM 64
#define TK 16

__global__ __launch_bounds__(256) void gemm_kernel(
    const float* __restrict__ X, const float* __restrict__ W,
    float* __restrict__ MX, int N)
{
    __shared__ float As[TK][TN + 4];
    __shared__ float Bs[TK][TM + 4];
    const int tid = threadIdx.x;
    const int tx = tid & 15, ty = tid >> 4;
    const int r0 = blockIdx.x * TN;
    const int c0 = blockIdx.y * TM;
    const int lr = tid >> 2;           // 0..63
    const int lk = (tid & 3) * 4;      // 0,4,8,12

    float acc[4][4] = {};

    for (int k0 = 0; k0 < D; k0 += TK) {
        int grow = r0 + lr;
        float4 av = make_float4(0.f, 0.f, 0.f, 0.f);
        if (grow < N) av = *(const float4*)(X + (size_t)grow * D + k0 + lk);
        As[lk + 0][lr] = av.x; As[lk + 1][lr] = av.y;
        As[lk + 2][lr] = av.z; As[lk + 3][lr] = av.w;
        float4 bv = *(const float4*)(W + (size_t)(c0 + lr) * D + k0 + lk);
        Bs[lk + 0][lr] = bv.x; Bs[lk + 1][lr] = bv.y;
        Bs[lk + 2][lr] = bv.z; Bs[lk + 3][lr] = bv.w;
        __syncthreads();

        #pragma unroll
        for (int kk = 0; kk < TK; ++kk) {
            float4 a = *(const float4*)&As[kk][ty * 4];
            float4 b = *(const float4*)&Bs[kk][tx * 4];
            float avr[4] = {a.x, a.y, a.z, a.w};
            float bvr[4] = {b.x, b.y, b.z, b.w};
            #pragma unroll
            for (int i = 0; i < 4; ++i)
                #pragma unroll
                for (int j = 0; j < 4; ++j)
                    acc[i][j] = fmaf(avr[i], bvr[j], acc[i][j]);
        }
        __syncthreads();
    }

    #pragma unroll
    for (int i = 0; i < 4; ++i) {
        int row = r0 + ty * 4 + i;
        if (row < N) {
            float4 o = make_float4(acc[i][0], acc[i][1], acc[i][2], acc[i][3]);
            *(float4*)(MX + (size_t)row * D + c0 + tx * 4) = o;
        }
    }
}

// ---------------------------------------------------------------------------
// Kernel 3: per-row hyperbolic ops  (one wave per row)
// ---------------------------------------------------------------------------
__global__ __launch_bounds__(256) void rowops_kernel(
    const float* __restrict__ X, const float* __restrict__ MX,
    const float* __restrict__ HB, float* __restrict__ XT, int N)
{
    int wave = (int)((blockIdx.x * (size_t)blockDim.x + threadIdx.x) >> 6);
    int l = threadIdx.x & 63;
    if (wave >= N) return;

    const float4 xv  = *(const float4*)(X  + (size_t)wave * D + 4 * l);
    const float4 mxv = *(const float4*)(MX + (size_t)wave * D + 4 * l);

    float xn  = fmaxf(sqrtf(wave_reduce_sum(dot4(xv,  xv))),  MIN_NORM);
    float mxn = fmaxf(sqrtf(wave_reduce_sum(dot4(mxv, mxv))), MIN_NORM);

    float r = (mxn / xn) * artanh_clip(xn);
    float f = tanhf(r) / mxn;
    float4 h = make_float4(mxv.x * f, mxv.y * f, mxv.z * f, mxv.w * f);

    float hss = wave_reduce_sum(dot4(h, h));
    float hn = fmaxf(sqrtf(hss), MIN_NORM);
    float s = (hn > MAXNORM) ? (MAXNORM / hn) : 1.0f;
    h.x *= s; h.y *= s; h.z *= s; h.w *= s;
    float x2 = hss * s * s;

    const float4 y = *(const float4*)(HB + 4 * l);
    float y2 = HB[D];
    float xy = wave_reduce_sum(dot4(h, y));
    float ch = 1.0f + 2.0f * xy + y2;
    float cy = 1.0f - x2;
    float den = fmaxf(1.0f + 2.0f * xy + x2 * y2, MIN_NORM);
    float inv = 1.0f / den;
    float4 g = make_float4((ch * h.x + cy * y.x) * inv,
                           (ch * h.y + cy * y.y) * inv,
                           (ch * h.z + cy * y.z) * inv,
                           (ch * h.w + cy * y.w) * inv);

    float gss = wave_reduce_sum(dot4(g, g));
    float gn = fmaxf(sqrtf(gss), MIN_NORM);
    float s2 = (gn > MAXNORM) ? (MAXNORM / gn) : 1.0f;
    g.x *= s2; g.y *= s2; g.z *= s2; g.w *= s2;

    float pn = fmaxf(gn * s2, MIN_NORM);
    float lf = artanh_clip(pn) / pn;
    float4 xt = make_float4(g.x * lf, g.y * lf, g.z * lf, g.w * lf);
    *(float4*)(XT + (size_t)wave * D + 4 * l) = xt;
}

// ---------------------------------------------------------------------------
// Kernel 4: sparse aggregation + HypAct   (one wave per node)
// rowptr lookup (no binary search) + shfl-broadcast cols/vals + 8-deep
// pipelined independent gathers. Tail padded with (col=0, val=0): row 0 stays
// L2-hot and the FMA adds zero, so the unrolled body needs no tail loop.
// ---------------------------------------------------------------------------
__global__ __launch_bounds__(256) void agg_kernel(
    const int* __restrict__ rowptr, const int* __restrict__ cols,
    const float* __restrict__ vals, const float* __restrict__ XT,
    float* __restrict__ OUT, int N)
{
    int node = (int)((blockIdx.x * (size_t)blockDim.x + threadIdx.x) >> 6);
    int l = threadIdx.x & 63;
    if (node >= N) return;

    int start = rowptr[node];
    int end   = rowptr[node + 1];

    const float4* xt4 = (const float4*)XT;
    float4 acc = make_float4(0.f, 0.f, 0.f, 0.f);

    for (int base = start; base < end; base += 64) {
        int idx = base + l;
        bool ok = idx < end;
        int   myc = ok ? cols[idx] : 0;
        float myv = ok ? vals[idx] : 0.0f;
        int cnt = min(64, end - base);
        int cnt8 = (cnt + 7) & ~7;     // pad to 8; padded lanes have v=0, c=0

        for (int j = 0; j < cnt8; j += 8) {
            int   c[8];
            float v[8];
            #pragma unroll
            for (int u = 0; u < 8; ++u) {
                c[u] = __shfl(myc, j + u, 64);
                v[u] = __shfl(myv, j + u, 64);
            }
            float4 m[8];
            #pragma unroll
            for (int u = 0; u < 8; ++u)
                m[u] = xt4[(size_t)c[u] * 64 + l];
            #pragma unroll
            for (int u = 0; u < 8; ++u) {
                acc.x = fmaf(v[u], m[u].x, acc.x);
                acc.y = fmaf(v[u], m[u].y, acc.y);
                acc.z = fmaf(v[u], m[u].z, acc.z);
                acc.w = fmaf(v[u], m[u].w, acc.w);
            }
        }
    }

    // expmap0
    float un = fmaxf(sqrtf(wave_reduce_sum(dot4(acc, acc))), MIN_NORM);
    float f = tanhf(un) / un;
    float4 h = make_float4(acc.x * f, acc.y * f, acc.z * f, acc.w * f);
    // proj
    float hn = fmaxf(sqrtf(wave_reduce_sum(dot4(h, h))), MIN_NORM);
    float s = (hn > MAXNORM) ? (MAXNORM / hn) : 1.0f;
    h.x *= s; h.y *= s; h.z *= s; h.w *= s;
    // logmap0 + relu
    float pn = fmaxf(hn * s, MIN_NORM);
    float lf = artanh_clip(pn) / pn;
    float4 t = make_float4(fmaxf(h.x * lf, 0.f), fmaxf(h.y * lf, 0.f),
                           fmaxf(h.z * lf, 0.f), fmaxf(h.w * lf, 0.f));
    // expmap0 (c_out = 1)
    float un2 = fmaxf(sqrtf(wave_reduce_sum(dot4(t, t))), MIN_NORM);
    float f2 = tanhf(un2) / un2;
    float4 o = make_float4(t.x * f2, t.y * f2, t.z * f2, t.w * f2);
    // proj
    float on = fmaxf(sqrtf(wave_reduce_sum(dot4(o, o))), MIN_NORM);
    float s2 = (on > MAXNORM) ? (MAXNORM / on) : 1.0f;
    o.x *= s2; o.y *= s2; o.z *= s2; o.w *= s2;

    *(float4*)(OUT + (size_t)node * D + 4 * l) = o;
}

// ---------------------------------------------------------------------------
extern "C" void kernel_launch(void* const* d_in, const int* in_sizes, int n_in,
                              void* d_out, int out_size, void* d_ws, size_t ws_size,
                              hipStream_t stream) {
    const float* X    = (const float*)d_in[0];
    const float* W    = (const float*)d_in[1];
    const float* bias = (const float*)d_in[2];
    const float* vals = (const float*)d_in[3];
    const int*   rows = (const int*)d_in[4];
    const int*   cols = (const int*)d_in[5];
    float* OUT = (float*)d_out;

    const int N = in_sizes[0] / D;   // 10000
    const int E = in_sizes[3];       // 320000

    // ws layout: rowptr [N+1 ints] | HB [512 floats] | XT [N*256 floats]
    int*   rowptr = (int*)d_ws;
    float* HB = (float*)d_ws + ((N + 1 + 127) & ~127);
    float* XT = HB + 512;
    float* MX = OUT;                 // d_out as GEMM scratch; overwritten by agg

    bias_kernel<<<1, 64, 0, stream>>>(bias, HB);
    rowptr_kernel<<<(E + 255) / 256, 256, 0, stream>>>(rows, rowptr, N, E);
    dim3 ggrid((N + TN - 1) / TN, D / TM);
    gemm_kernel<<<ggrid, 256, 0, stream>>>(X, W, MX, N);
    int wave_blocks = (N + 3) / 4;   // 4 waves per 256-thread block
    rowops_kernel<<<wave_blocks, 256, 0, stream>>>(X, MX, HB, XT, N);
    agg_kernel<<<wave_blocks, 256, 0, stream>>>(rowptr, cols, vals, XT, OUT, N);
}

// Round 3
// 122.669 us; speedup vs baseline: 1.4643x; 1.2005x over previous
//
#include <hip/hip_runtime.h>
#include <math.h>

#define D 256            // feature dim (D_IN == D_OUT == 256)
#define MAXNORM (1.0f - 4e-3f)   // (1 - BALL_EPS)/sqrt(c), c = 1
#define MIN_NORM 1e-15f

typedef _Float16 v8h __attribute__((ext_vector_type(8)));
typedef _Float16 h4  __attribute__((ext_vector_type(4)));
typedef float    v4f __attribute__((ext_vector_type(4)));

__device__ __forceinline__ float wave_reduce_sum(float v) {
    #pragma unroll
    for (int m = 32; m >= 1; m >>= 1) v += __shfl_xor(v, m, 64);
    return v;
}

__device__ __forceinline__ float dot4(const float4& a, const float4& b) {
    return a.x * b.x + a.y * b.y + a.z * b.z + a.w * b.w;
}

__device__ __forceinline__ float artanh_clip(float x) {
    x = fminf(fmaxf(x, -1.0f + 1e-7f), 1.0f - 1e-7f);
    return 0.5f * (log1pf(x) - log1pf(-x));
}

// ---------------------------------------------------------------------------
// Kernel 1: hyp_bias = proj(expmap0(bias, c=1), c=1); also store ||hyp_bias||^2
// ---------------------------------------------------------------------------
__global__ void bias_kernel(const float* __restrict__ bias, float* __restrict__ hb) {
    int l = threadIdx.x;  // 0..63
    float4 v = *(const float4*)(bias + 4 * l);
    float bn = fmaxf(sqrtf(wave_reduce_sum(dot4(v, v))), MIN_NORM);
    float f = tanhf(bn) / bn;
    float4 h = make_float4(v.x * f, v.y * f, v.z * f, v.w * f);
    float hn = fmaxf(sqrtf(wave_reduce_sum(dot4(h, h))), MIN_NORM);
    float s = (hn > MAXNORM) ? (MAXNORM / hn) : 1.0f;
    h.x *= s; h.y *= s; h.z *= s; h.w *= s;
    *(float4*)(hb + 4 * l) = h;
    float y2 = wave_reduce_sum(dot4(h, h));
    if (l == 0) hb[D] = y2;
}

// ---------------------------------------------------------------------------
// Kernel 1b: row_ptr from sorted adj_row
// ---------------------------------------------------------------------------
__global__ __launch_bounds__(256) void rowptr_kernel(
    const int* __restrict__ rows, int* __restrict__ rowptr, int N, int E)
{
    int e = blockIdx.x * blockDim.x + threadIdx.x;
    if (e >= E) return;
    int r1 = rows[e];
    if (e == 0) {
        for (int r = 0; r <= r1; ++r) rowptr[r] = 0;
    } else {
        int r0 = rows[e - 1];
        for (int r = r0 + 1; r <= r1; ++r) rowptr[r] = e;
    }
    if (e == E - 1) {
        for (int r = r1 + 1; r <= N; ++r) rowptr[r] = E;
    }
}

// ---------------------------------------------------------------------------
// Kernel 1c: W (fp32, 256x256) -> Wh (fp16)
// ---------------------------------------------------------------------------
__global__ __launch_bounds__(256) void wcast_kernel(
    const float* __restrict__ W, _Float16* __restrict__ Wh)
{
    int i = blockIdx.x * blockDim.x + threadIdx.x;   // float4 index, 16384 total
    float4 v = ((const float4*)W)[i];
    h4 o; o[0] = (_Float16)v.x; o[1] = (_Float16)v.y;
    o[2] = (_Float16)v.z; o[3] = (_Float16)v.w;
    *(h4*)(Wh + 4 * (size_t)i) = o;
}

// ---------------------------------------------------------------------------
// Kernel 2: MX = X @ W^T via fp16 MFMA (fp32 accumulate). Also XNSQ = ||x_row||^2
// (computed from fp32 X during staging).
// Block: 256 threads (4 waves), 32 rows x 256 cols. Wave w: cols [64w, 64w+64).
// A staged once: 32 rows x 256 k fp16 in LDS (stride 264 halves: +8 pad ->
// rows r, r+8 alias a bank pair = 2-way = free).
// Frag layouts (verified m89/m120): A[m=lane&15][k=quad*8+j],
// B[k=quad*8+j][n=lane&15] = Wh[col=n][k..k+7] contiguous, C: col=lane&15,
// row=quad*4+reg.
// ---------------------------------------------------------------------------
#define AS_STRIDE 264

__global__ __launch_bounds__(256) void gemm_kernel(
    const float* __restrict__ X, const _Float16* __restrict__ Wh,
    float* __restrict__ MX, float* __restrict__ XNSQ, int N)
{
    __shared__ _Float16 As[32 * AS_STRIDE];
    const int t = threadIdx.x;
    const int r0 = blockIdx.x * 32;

    // ---- stage X rows [r0, r0+32) as fp16, compute row sumsq in fp32 ----
    {
        const int r = t >> 3;        // 0..31
        const int q = t & 7;         // 0..7
        const int grow = r0 + r;
        float ss = 0.0f;
        #pragma unroll
        for (int j = 0; j < 8; ++j) {
            const int fi = q + j * 8;   // float4 index within row, 0..63
            float4 v = make_float4(0.f, 0.f, 0.f, 0.f);
            if (grow < N) v = ((const float4*)X)[(size_t)grow * 64 + fi];
            ss += dot4(v, v);
            h4 hv; hv[0] = (_Float16)v.x; hv[1] = (_Float16)v.y;
            hv[2] = (_Float16)v.z; hv[3] = (_Float16)v.w;
            *(h4*)&As[r * AS_STRIDE + fi * 4] = hv;
        }
        ss += __shfl_xor(ss, 1, 64);
        ss += __shfl_xor(ss, 2, 64);
        ss += __shfl_xor(ss, 4, 64);
        if (q == 0 && grow < N) XNSQ[grow] = ss;
    }
    __syncthreads();

    // ---- MFMA compute ----
    const int w  = t >> 6;       // wave 0..3 -> col block
    const int l  = t & 63;
    const int lm = l & 15;
    const int q  = l >> 4;

    v4f acc[2][4];
    #pragma unroll
    for (int a = 0; a < 2; ++a)
        #pragma unroll
        for (int b = 0; b < 4; ++b)
            #pragma unroll
            for (int i = 0; i < 4; ++i) acc[a][b][i] = 0.0f;

    const _Float16* WhB = Wh + (size_t)(64 * w + lm) * 256 + q * 8;

    #pragma unroll
    for (int kc = 0; kc < 8; ++kc) {
        const int k = kc * 32 + q * 8;
        v8h a0 = *(const v8h*)&As[(0  + lm) * AS_STRIDE + k];
        v8h a1 = *(const v8h*)&As[(16 + lm) * AS_STRIDE + k];
        #pragma unroll
        for (int ct = 0; ct < 4; ++ct) {
            v8h b = *(const v8h*)(WhB + (size_t)ct * 16 * 256 + kc * 32);
            acc[0][ct] = __builtin_amdgcn_mfma_f32_16x16x32_f16(a0, b, acc[0][ct], 0, 0, 0);
            acc[1][ct] = __builtin_amdgcn_mfma_f32_16x16x32_f16(a1, b, acc[1][ct], 0, 0, 0);
        }
    }

    #pragma unroll
    for (int rt = 0; rt < 2; ++rt)
        #pragma unroll
        for (int ct = 0; ct < 4; ++ct)
            #pragma unroll
            for (int i = 0; i < 4; ++i) {
                const int row = r0 + rt * 16 + q * 4 + i;
                if (row < N)
                    MX[(size_t)row * 256 + 64 * w + ct * 16 + lm] = acc[rt][ct][i];
            }
}

// ---------------------------------------------------------------------------
// Kernel 3: per-row hyperbolic ops (one wave per row); XT written as fp16
// ---------------------------------------------------------------------------
__global__ __launch_bounds__(256) void rowops_kernel(
    const float* __restrict__ MX, const float* __restrict__ XNSQ,
    const float* __restrict__ HB, _Float16* __restrict__ XT, int N)
{
    int wave = (int)((blockIdx.x * (size_t)blockDim.x + threadIdx.x) >> 6);
    int l = threadIdx.x & 63;
    if (wave >= N) return;

    const float4 mxv = *(const float4*)(MX + (size_t)wave * D + 4 * l);
    float xn  = fmaxf(sqrtf(XNSQ[wave]), MIN_NORM);
    float mxn = fmaxf(sqrtf(wave_reduce_sum(dot4(mxv, mxv))), MIN_NORM);

    float r = (mxn / xn) * artanh_clip(xn);
    float f = tanhf(r) / mxn;
    float4 h = make_float4(mxv.x * f, mxv.y * f, mxv.z * f, mxv.w * f);

    float hss = wave_reduce_sum(dot4(h, h));
    float hn = fmaxf(sqrtf(hss), MIN_NORM);
    float s = (hn > MAXNORM) ? (MAXNORM / hn) : 1.0f;
    h.x *= s; h.y *= s; h.z *= s; h.w *= s;
    float x2 = hss * s * s;

    const float4 y = *(const float4*)(HB + 4 * l);
    float y2 = HB[D];
    float xy = wave_reduce_sum(dot4(h, y));
    float ch = 1.0f + 2.0f * xy + y2;
    float cy = 1.0f - x2;
    float den = fmaxf(1.0f + 2.0f * xy + x2 * y2, MIN_NORM);
    float inv = 1.0f / den;
    float4 g = make_float4((ch * h.x + cy * y.x) * inv,
                           (ch * h.y + cy * y.y) * inv,
                           (ch * h.z + cy * y.z) * inv,
                           (ch * h.w + cy * y.w) * inv);

    float gss = wave_reduce_sum(dot4(g, g));
    float gn = fmaxf(sqrtf(gss), MIN_NORM);
    float s2 = (gn > MAXNORM) ? (MAXNORM / gn) : 1.0f;
    g.x *= s2; g.y *= s2; g.z *= s2; g.w *= s2;

    float pn = fmaxf(gn * s2, MIN_NORM);
    float lf = artanh_clip(pn) / pn;
    h4 xt; xt[0] = (_Float16)(g.x * lf); xt[1] = (_Float16)(g.y * lf);
    xt[2] = (_Float16)(g.z * lf); xt[3] = (_Float16)(g.w * lf);
    *(h4*)(XT + (size_t)wave * D + 4 * l) = xt;
}

// ---------------------------------------------------------------------------
// Kernel 4: sparse aggregation (fp16 gather, fp32 accum) + HypAct
// ---------------------------------------------------------------------------
__global__ __launch_bounds__(256) void agg_kernel(
    const int* __restrict__ rowptr, const int* __restrict__ cols,
    const float* __restrict__ vals, const _Float16* __restrict__ XT,
    float* __restrict__ OUT, int N)
{
    int node = (int)((blockIdx.x * (size_t)blockDim.x + threadIdx.x) >> 6);
    int l = threadIdx.x & 63;
    if (node >= N) return;

    int start = rowptr[node];
    int end   = rowptr[node + 1];

    const h4* xt4 = (const h4*)XT;
    float4 acc = make_float4(0.f, 0.f, 0.f, 0.f);

    for (int base = start; base < end; base += 64) {
        int idx = base + l;
        bool ok = idx < end;
        int   myc = ok ? cols[idx] : 0;
        float myv = ok ? vals[idx] : 0.0f;
        int cnt = min(64, end - base);
        int cnt8 = (cnt + 7) & ~7;     // pad to 8; padded lanes v=0, c=0

        for (int j = 0; j < cnt8; j += 8) {
            int   c[8];
            float v[8];
            #pragma unroll
            for (int u = 0; u < 8; ++u) {
                c[u] = __shfl(myc, j + u, 64);
                v[u] = __shfl(myv, j + u, 64);
            }
            h4 m[8];
            #pragma unroll
            for (int u = 0; u < 8; ++u)
                m[u] = xt4[(size_t)c[u] * 64 + l];
            #pragma unroll
            for (int u = 0; u < 8; ++u) {
                acc.x = fmaf(v[u], (float)m[u][0], acc.x);
                acc.y = fmaf(v[u], (float)m[u][1], acc.y);
                acc.z = fmaf(v[u], (float)m[u][2], acc.z);
                acc.w = fmaf(v[u], (float)m[u][3], acc.w);
            }
        }
    }

    // expmap0
    float un = fmaxf(sqrtf(wave_reduce_sum(dot4(acc, acc))), MIN_NORM);
    float f = tanhf(un) / un;
    float4 h = make_float4(acc.x * f, acc.y * f, acc.z * f, acc.w * f);
    // proj
    float hn = fmaxf(sqrtf(wave_reduce_sum(dot4(h, h))), MIN_NORM);
    float s = (hn > MAXNORM) ? (MAXNORM / hn) : 1.0f;
    h.x *= s; h.y *= s; h.z *= s; h.w *= s;
    // logmap0 + relu
    float pn = fmaxf(hn * s, MIN_NORM);
    float lf = artanh_clip(pn) / pn;
    float4 tt = make_float4(fmaxf(h.x * lf, 0.f), fmaxf(h.y * lf, 0.f),
                            fmaxf(h.z * lf, 0.f), fmaxf(h.w * lf, 0.f));
    // expmap0 (c_out = 1)
    float un2 = fmaxf(sqrtf(wave_reduce_sum(dot4(tt, tt))), MIN_NORM);
    float f2 = tanhf(un2) / un2;
    float4 o = make_float4(tt.x * f2, tt.y * f2, tt.z * f2, tt.w * f2);
    // proj
    float on = fmaxf(sqrtf(wave_reduce_sum(dot4(o, o))), MIN_NORM);
    float s2 = (on > MAXNORM) ? (MAXNORM / on) : 1.0f;
    o.x *= s2; o.y *= s2; o.z *= s2; o.w *= s2;

    *(float4*)(OUT + (size_t)node * D + 4 * l) = o;
}

// ---------------------------------------------------------------------------
extern "C" void kernel_launch(void* const* d_in, const int* in_sizes, int n_in,
                              void* d_out, int out_size, void* d_ws, size_t ws_size,
                              hipStream_t stream) {
    const float* X    = (const float*)d_in[0];
    const float* W    = (const float*)d_in[1];
    const float* bias = (const float*)d_in[2];
    const float* vals = (const float*)d_in[3];
    const int*   rows = (const int*)d_in[4];
    const int*   cols = (const int*)d_in[5];
    float* OUT = (float*)d_out;

    const int N = in_sizes[0] / D;   // 10000
    const int E = in_sizes[3];       // 320000

    // ws layout (floats): rowptr [N+1 -> 10240 ints] | HB [512] | XNSQ [10240]
    //                     | Wh [65536 halves = 16384 floats] | XT [N*256 halves]
    int*   rowptr = (int*)d_ws;
    float* HB   = (float*)d_ws + 10240;
    float* XNSQ = HB + 512;
    _Float16* Wh = (_Float16*)(XNSQ + 10240);
    _Float16* XT = (_Float16*)((float*)(void*)Wh + 16384 + 64);
    float* MX = OUT;                 // d_out as GEMM scratch; overwritten by agg

    bias_kernel<<<1, 64, 0, stream>>>(bias, HB);
    rowptr_kernel<<<(E + 255) / 256, 256, 0, stream>>>(rows, rowptr, N, E);
    wcast_kernel<<<64, 256, 0, stream>>>(W, Wh);
    gemm_kernel<<<(N + 31) / 32, 256, 0, stream>>>(X, Wh, MX, XNSQ, N);
    int wave_blocks = (N + 3) / 4;   // 4 waves per 256-thread block
    rowops_kernel<<<wave_blocks, 256, 0, stream>>>(MX, XNSQ, HB, XT, N);
    agg_kernel<<<wave_blocks, 256, 0, stream>>>(rowptr, cols, vals, XT, OUT, N);
}

// Round 4
// 110.606 us; speedup vs baseline: 1.6240x; 1.1091x over previous
//
#include <hip/hip_runtime.h>
#include <math.h>

#define D 256            // feature dim (D_IN == D_OUT == 256)
#define MAXNORM (1.0f - 4e-3f)   // (1 - BALL_EPS)/sqrt(c), c = 1
#define MIN_NORM 1e-15f

typedef _Float16 v8h __attribute__((ext_vector_type(8)));
typedef _Float16 h4  __attribute__((ext_vector_type(4)));
typedef float    v4f __attribute__((ext_vector_type(4)));

__device__ __forceinline__ float wave_reduce_sum(float v) {
    #pragma unroll
    for (int m = 32; m >= 1; m >>= 1) v += __shfl_xor(v, m, 64);
    return v;
}

__device__ __forceinline__ float dot4(const float4& a, const float4& b) {
    return a.x * b.x + a.y * b.y + a.z * b.z + a.w * b.w;
}

__device__ __forceinline__ float artanh_clip(float x) {
    x = fminf(fmaxf(x, -1.0f + 1e-7f), 1.0f - 1e-7f);
    return 0.5f * (log1pf(x) - log1pf(-x));
}

// ---------------------------------------------------------------------------
// Kernel 1 (prep): fuses
//   (a) rowptr fill from sorted adj_row          [all blocks, e < E]
//   (b) W fp32 -> fp16 cast                      [blocks 0..63]
//   (c) hyp_bias = proj(expmap0(bias)) + ||.||^2 [block 64, wave 0]
// ---------------------------------------------------------------------------
__global__ __launch_bounds__(256) void prep_kernel(
    const float* __restrict__ bias, const float* __restrict__ W,
    const int* __restrict__ rows,
    float* __restrict__ HB, _Float16* __restrict__ Wh,
    int* __restrict__ rowptr, int N, int E)
{
    const int b = blockIdx.x, t = threadIdx.x;
    const int e = b * 256 + t;

    if (e < E) {
        int r1 = rows[e];
        if (e == 0) {
            for (int r = 0; r <= r1; ++r) rowptr[r] = 0;
        } else {
            int r0 = rows[e - 1];
            for (int r = r0 + 1; r <= r1; ++r) rowptr[r] = e;
        }
        if (e == E - 1) {
            for (int r = r1 + 1; r <= N; ++r) rowptr[r] = E;
        }
    }

    if (b < 64) {   // W cast: 64 blocks x 256 threads x float4 = 65536 floats
        int i = b * 256 + t;
        float4 v = ((const float4*)W)[i];
        h4 o; o[0] = (_Float16)v.x; o[1] = (_Float16)v.y;
        o[2] = (_Float16)v.z; o[3] = (_Float16)v.w;
        *(h4*)(Wh + 4 * (size_t)i) = o;
    }

    if (b == 64 && t < 64) {   // bias (single wave)
        int l = t;
        float4 v = *(const float4*)(bias + 4 * l);
        float bn = fmaxf(sqrtf(wave_reduce_sum(dot4(v, v))), MIN_NORM);
        float f = tanhf(bn) / bn;
        float4 h = make_float4(v.x * f, v.y * f, v.z * f, v.w * f);
        float hn = fmaxf(sqrtf(wave_reduce_sum(dot4(h, h))), MIN_NORM);
        float s = (hn > MAXNORM) ? (MAXNORM / hn) : 1.0f;
        h.x *= s; h.y *= s; h.z *= s; h.w *= s;
        *(float4*)(HB + 4 * l) = h;
        float y2 = wave_reduce_sum(dot4(h, h));
        if (l == 0) HB[D] = y2;
    }
}

// ---------------------------------------------------------------------------
// Kernel 2 (fused GEMM + rowops): XT = rowops(X @ W^T) in one pass.
// Algebra: the whole HypLinear tail collapses to
//   xt[row][col] = A[row]*mx[row][col] + B[row]*y[col]
// with A,B from three per-row scalars: ||x||^2 (staging), ||mx||^2 and
// <mx,y> (fragment reductions). mx never leaves registers.
// Block: 256 threads (4 waves), 16 rows x 256 cols; wave w = cols [64w,64w+64).
// Frag layouts (verified m89/m120): A[m=lane&15][k=quad*8+j],
// B[k=quad*8+j][n=lane&15] (Wh[col][k..k+7] contiguous), C: col=lane&15,
// row=quad*4+reg.
// ---------------------------------------------------------------------------
#define AS16 264   // LDS row stride in halves (+8 pad)

__global__ __launch_bounds__(256) void gemmrow_kernel(
    const float* __restrict__ X, const _Float16* __restrict__ Wh,
    const float* __restrict__ HB, _Float16* __restrict__ XT, int N)
{
    __shared__ _Float16 As[16 * AS16];
    __shared__ float xnsq[16];
    __shared__ float part_s[16][4];
    __shared__ float part_d[16][4];
    __shared__ float Arow[16], Brow[16];

    const int t = threadIdx.x;
    const int r0 = blockIdx.x * 16;

    // ---- stage X rows [r0, r0+16) as fp16; per-row ||x||^2 in fp32 ----
    {
        const int r = t >> 4, q2 = t & 15;
        const int grow = r0 + r;
        float ss = 0.0f;
        #pragma unroll
        for (int j = 0; j < 4; ++j) {
            const int fi = q2 + j * 16;
            float4 v = make_float4(0.f, 0.f, 0.f, 0.f);
            if (grow < N) v = ((const float4*)X)[(size_t)grow * 64 + fi];
            ss += dot4(v, v);
            h4 hv; hv[0] = (_Float16)v.x; hv[1] = (_Float16)v.y;
            hv[2] = (_Float16)v.z; hv[3] = (_Float16)v.w;
            *(h4*)&As[r * AS16 + fi * 4] = hv;
        }
        ss += __shfl_xor(ss, 1, 64);
        ss += __shfl_xor(ss, 2, 64);
        ss += __shfl_xor(ss, 4, 64);
        ss += __shfl_xor(ss, 8, 64);
        if (q2 == 0) xnsq[r] = ss;
    }
    __syncthreads();

    // ---- MFMA: wave w computes rows 0..15 x cols [64w, 64w+64) ----
    const int w  = t >> 6;
    const int l  = t & 63;
    const int lm = l & 15;
    const int q  = l >> 4;

    v4f acc[4];
    #pragma unroll
    for (int ct = 0; ct < 4; ++ct)
        #pragma unroll
        for (int i = 0; i < 4; ++i) acc[ct][i] = 0.0f;

    const _Float16* WhB = Wh + (size_t)(64 * w + lm) * 256 + q * 8;

    #pragma unroll
    for (int kc = 0; kc < 8; ++kc) {
        v8h a = *(const v8h*)&As[lm * AS16 + kc * 32 + q * 8];
        #pragma unroll
        for (int ct = 0; ct < 4; ++ct) {
            v8h bfr = *(const v8h*)(WhB + (size_t)ct * 16 * 256 + kc * 32);
            acc[ct] = __builtin_amdgcn_mfma_f32_16x16x32_f16(a, bfr, acc[ct], 0, 0, 0);
        }
    }

    // y values for this lane's 4 columns
    float yv[4];
    #pragma unroll
    for (int ct = 0; ct < 4; ++ct) yv[ct] = HB[64 * w + ct * 16 + lm];

    // ---- per-row reductions: s = sum mx^2, d = <mx, y> (64 cols of wave w) ----
    {
        float s_[4], d_[4];
        #pragma unroll
        for (int i = 0; i < 4; ++i) {
            float s = 0.f, d = 0.f;
            #pragma unroll
            for (int ct = 0; ct < 4; ++ct) {
                float v = acc[ct][i];
                s = fmaf(v, v, s);
                d = fmaf(v, yv[ct], d);
            }
            #pragma unroll
            for (int m = 1; m <= 8; m <<= 1) {
                s += __shfl_xor(s, m, 64);
                d += __shfl_xor(d, m, 64);
            }
            s_[i] = s; d_[i] = d;
        }
        if (lm == 0) {
            #pragma unroll
            for (int i = 0; i < 4; ++i) {
                part_s[q * 4 + i][w] = s_[i];
                part_d[q * 4 + i][w] = d_[i];
            }
        }
    }
    __syncthreads();

    // ---- per-row scalar chain (exact rowops algebra, fp32) ----
    if (t < 16) {
        float mx2 = part_s[t][0] + part_s[t][1] + part_s[t][2] + part_s[t][3];
        float mxy = part_d[t][0] + part_d[t][1] + part_d[t][2] + part_d[t][3];
        float y2  = HB[D];
        float xn  = fmaxf(sqrtf(xnsq[t]), MIN_NORM);
        float mxn = fmaxf(sqrtf(mx2), MIN_NORM);
        // mobius_matvec tail: h = tanh(mxn/xn * artanh(xn)) * mx / mxn
        float r  = (mxn / xn) * artanh_clip(xn);
        float th = tanhf(r);              // = ||h|| before proj (>= 0)
        float f  = th / mxn;
        float hn = fmaxf(th, MIN_NORM);
        float s  = (hn > MAXNORM) ? (MAXNORM / hn) : 1.0f;
        float fs = f * s;                 // h = fs * mx
        float x2 = th * th * s * s;       // ||h||^2 after proj
        // mobius_add(h, y)
        float xy  = fs * mxy;
        float ch  = 1.0f + 2.0f * xy + y2;
        float cy  = 1.0f - x2;
        float inv = 1.0f / fmaxf(1.0f + 2.0f * xy + x2 * y2, MIN_NORM);
        float alpha = ch * fs * inv;      // g = alpha*mx + beta*y
        float beta  = cy * inv;
        // proj(g) + logmap0
        float gss = alpha * alpha * mx2 + 2.0f * alpha * beta * mxy + beta * beta * y2;
        float gn  = fmaxf(sqrtf(gss), MIN_NORM);
        float s2  = (gn > MAXNORM) ? (MAXNORM / gn) : 1.0f;
        float pn  = fmaxf(gn * s2, MIN_NORM);
        float lf  = artanh_clip(pn) / pn;
        Arow[t] = lf * s2 * alpha;
        Brow[t] = lf * s2 * beta;
    }
    __syncthreads();

    // ---- write XT = A*mx + B*y as fp16, straight from fragments ----
    #pragma unroll
    for (int i = 0; i < 4; ++i) {
        const int rr = q * 4 + i;
        const int row = r0 + rr;
        if (row < N) {
            float A = Arow[rr], B = Brow[rr];
            #pragma unroll
            for (int ct = 0; ct < 4; ++ct) {
                float v = fmaf(A, acc[ct][i], B * yv[ct]);
                XT[(size_t)row * 256 + 64 * w + ct * 16 + lm] = (_Float16)v;
            }
        }
    }
}

// ---------------------------------------------------------------------------
// Kernel 3: sparse aggregation (fp16 gather, fp32 accum) + HypAct
// One wave per node; shfl-broadcast cols/vals; 8-deep pipelined gathers.
// ---------------------------------------------------------------------------
__global__ __launch_bounds__(256) void agg_kernel(
    const int* __restrict__ rowptr, const int* __restrict__ cols,
    const float* __restrict__ vals, const _Float16* __restrict__ XT,
    float* __restrict__ OUT, int N)
{
    int node = (int)((blockIdx.x * (size_t)blockDim.x + threadIdx.x) >> 6);
    int l = threadIdx.x & 63;
    if (node >= N) return;

    int start = rowptr[node];
    int end   = rowptr[node + 1];

    const h4* xt4 = (const h4*)XT;
    float4 acc = make_float4(0.f, 0.f, 0.f, 0.f);

    for (int base = start; base < end; base += 64) {
        int idx = base + l;
        bool ok = idx < end;
        int   myc = ok ? cols[idx] : 0;
        float myv = ok ? vals[idx] : 0.0f;
        int cnt = min(64, end - base);
        int cnt8 = (cnt + 7) & ~7;     // pad to 8; padded lanes v=0, c=0

        for (int j = 0; j < cnt8; j += 8) {
            int   c[8];
            float v[8];
            #pragma unroll
            for (int u = 0; u < 8; ++u) {
                c[u] = __shfl(myc, j + u, 64);
                v[u] = __shfl(myv, j + u, 64);
            }
            h4 m[8];
            #pragma unroll
            for (int u = 0; u < 8; ++u)
                m[u] = xt4[(size_t)c[u] * 64 + l];
            #pragma unroll
            for (int u = 0; u < 8; ++u) {
                acc.x = fmaf(v[u], (float)m[u][0], acc.x);
                acc.y = fmaf(v[u], (float)m[u][1], acc.y);
                acc.z = fmaf(v[u], (float)m[u][2], acc.z);
                acc.w = fmaf(v[u], (float)m[u][3], acc.w);
            }
        }
    }

    // expmap0
    float un = fmaxf(sqrtf(wave_reduce_sum(dot4(acc, acc))), MIN_NORM);
    float f = tanhf(un) / un;
    float4 h = make_float4(acc.x * f, acc.y * f, acc.z * f, acc.w * f);
    // proj
    float hn = fmaxf(sqrtf(wave_reduce_sum(dot4(h, h))), MIN_NORM);
    float s = (hn > MAXNORM) ? (MAXNORM / hn) : 1.0f;
    h.x *= s; h.y *= s; h.z *= s; h.w *= s;
    // logmap0 + relu
    float pn = fmaxf(hn * s, MIN_NORM);
    float lf = artanh_clip(pn) / pn;
    float4 tt = make_float4(fmaxf(h.x * lf, 0.f), fmaxf(h.y * lf, 0.f),
                            fmaxf(h.z * lf, 0.f), fmaxf(h.w * lf, 0.f));
    // expmap0 (c_out = 1)
    float un2 = fmaxf(sqrtf(wave_reduce_sum(dot4(tt, tt))), MIN_NORM);
    float f2 = tanhf(un2) / un2;
    float4 o = make_float4(tt.x * f2, tt.y * f2, tt.z * f2, tt.w * f2);
    // proj
    float on = fmaxf(sqrtf(wave_reduce_sum(dot4(o, o))), MIN_NORM);
    float s2 = (on > MAXNORM) ? (MAXNORM / on) : 1.0f;
    o.x *= s2; o.y *= s2; o.z *= s2; o.w *= s2;

    *(float4*)(OUT + (size_t)node * D + 4 * l) = o;
}

// ---------------------------------------------------------------------------
extern "C" void kernel_launch(void* const* d_in, const int* in_sizes, int n_in,
                              void* d_out, int out_size, void* d_ws, size_t ws_size,
                              hipStream_t stream) {
    const float* X    = (const float*)d_in[0];
    const float* W    = (const float*)d_in[1];
    const float* bias = (const float*)d_in[2];
    const float* vals = (const float*)d_in[3];
    const int*   rows = (const int*)d_in[4];
    const int*   cols = (const int*)d_in[5];
    float* OUT = (float*)d_out;

    const int N = in_sizes[0] / D;   // 10000
    const int E = in_sizes[3];       // 320000

    // ws layout (float units): rowptr [10240] | HB [512] | Wh [32768] | XT [...]
    int*      rowptr = (int*)d_ws;
    float*    HB = (float*)d_ws + 10240;
    _Float16* Wh = (_Float16*)((float*)d_ws + 10240 + 512);
    _Float16* XT = (_Float16*)((float*)d_ws + 10240 + 512 + 32768);

    prep_kernel<<<(E + 255) / 256, 256, 0, stream>>>(bias, W, rows, HB, Wh, rowptr, N, E);
    gemmrow_kernel<<<(N + 15) / 16, 256, 0, stream>>>(X, Wh, HB, XT, N);
    int wave_blocks = (N + 3) / 4;   // 4 waves per 256-thread block
    agg_kernel<<<wave_blocks, 256, 0, stream>>>(rowptr, cols, vals, XT, OUT, N);
}